// Round 3
// baseline (710.375 us; speedup 1.0000x reference)
//
#include <hip/hip_runtime.h>
#include <math.h>

// Problem constants
#define NH   7        // hazards
#define NROW 16384    // B*S = 8*2048
#define DD   768      // hidden dim
#define KK   64       // bottleneck dim
#define THRG 0.05f

typedef float  f32x4   __attribute__((ext_vector_type(4)));
typedef __bf16 bf16x8  __attribute__((ext_vector_type(8)));
typedef short  short8v __attribute__((ext_vector_type(8)));
typedef short  short4v __attribute__((ext_vector_type(4)));

union V8 { short8v s; bf16x8 b; };

__device__ __forceinline__ unsigned short f2bf(float f) {
  unsigned u = __float_as_uint(f);
  u = (u + 0x7FFFu + ((u >> 16) & 1u)) >> 16;   // round-to-nearest-even
  return (unsigned short)u;
}

__device__ __forceinline__ float gate_of(const float* __restrict__ M, int s, int t) {
  float m = M[s * NH + t];
  return (s != t && fabsf(m) > THRG) ? m : 0.0f;
}

__device__ __forceinline__ float gelu_t(float v) {
  float u = 0.7978845608028654f * (v + 0.044715f * v * v * v);
  return v / (1.0f + __expf(-2.0f * u));   // v * sigmoid(2u)
}

// async 16B global -> LDS copy; lds ptr must be the WAVE-uniform base (HW adds lane*16)
__device__ __forceinline__ void gload_lds16(const void* g, void* l) {
  __builtin_amdgcn_global_load_lds(
      (const __attribute__((address_space(1))) unsigned int*)g,
      (__attribute__((address_space(3))) unsigned int*)l, 16, 0, 0);
}

// ---- prep: W1 [s][t][d][k] f32 -> W1P [pr][kc][kcol(64)][dl(64)] bf16,
// PRE-SWIZZLED (inverse of the LDS read XOR) so global_load_lds can copy linearly.
__global__ void prep_w1(const float* __restrict__ W1, unsigned short* __restrict__ W1P) {
  int pr = blockIdx.x;                       // pr = s*7+t
  const float* src = W1 + (size_t)pr * DD * KK;
  unsigned short* dst = W1P + (size_t)pr * 12 * 4096;
  for (int idx = threadIdx.x; idx < 12 * 4096; idx += blockDim.x) {
    int kc = idx >> 12, rem = idx & 4095;
    int kcol = rem >> 6, dl = rem & 63;
    int dl_log = dl ^ ((kcol & 7) << 3);     // elem-space inverse of byte XOR ((row&7)<<4)
    dst[idx] = f2bf(src[(size_t)(kc * 64 + dl_log) * KK + kcol]);
  }
}

// ---- prep: W2 [s][t][k][d] f32 -> W2P [t][s][d(768)][k(64)] bf16, gate folded.
__global__ void prep_w2(const float* __restrict__ M, const float* __restrict__ W2,
                        unsigned short* __restrict__ W2P) {
  int st = blockIdx.x;                       // st = s*7+t
  int s = st / NH, t = st % NH;
  float g = gate_of(M, s, t);
  const float* src = W2 + (size_t)st * KK * DD;
  unsigned short* dst = W2P + (size_t)(t * NH + s) * DD * KK;
  for (int idx = threadIdx.x; idx < DD * KK; idx += blockDim.x) {
    int d = idx >> 6, k = idx & 63;
    dst[idx] = f2bf(g * src[(size_t)k * DD + d]);
  }
}

// ---- prep: b2sum[t][d] = sum_s gate(s,t) * b2[s][t][d]
__global__ void prep_b2(const float* __restrict__ M, const float* __restrict__ b2,
                        float* __restrict__ b2sum) {
  int idx = blockIdx.x * blockDim.x + threadIdx.x;
  if (idx >= NH * DD) return;
  int t = idx / DD, d = idx % DD;
  float acc = 0.f;
  for (int s = 0; s < NH; ++s)
    acc += gate_of(M, s, t) * b2[(size_t)(s * NH + t) * DD + d];
  b2sum[idx] = acc;
}

// ---- Phase A: H[pr][rb] (blocked 16KB, XOR-swizzled) = gelu(x[s] W1[s,t] + b1), bf16.
// x B-fragments are 8 CONTIGUOUS d-elems/lane -> load straight from global (L2-hot)
// and cvt in-register; no x LDS round-trip, no cross-lane repack. W1 double-buffered
// via global_load_lds (pre-swizzled source). One barrier per kc step; x prefetched
// one step ahead in registers.
__global__ __launch_bounds__(256, 4)
void chiA(const float* __restrict__ x, const float* __restrict__ M,
          const unsigned short* __restrict__ W1P, const float* __restrict__ b1,
          unsigned short* __restrict__ H) {
  __shared__ __align__(16) unsigned short w1s[2][64 * 64];   // 2 x 8 KB, swizzled [kcol][d]

  int bid = (int)blockIdx.x;
  int nid = (bid & 7) * 784 + (bid >> 3);   // 6272 = 8*784; t innermost -> L2 reuse of x chunk
  int rb = nid / 49, pr = nid % 49;
  int s = pr / NH, t = pr % NH;
  if (gate_of(M, s, t) == 0.0f) return;
  int row0 = rb * 128;

  int tid = (int)threadIdx.x;
  int wid = tid >> 6, lane = tid & 63, l16 = lane & 15, l4 = lane >> 4;

  const char* w1b = (const char*)(W1P + (size_t)pr * 12 * 4096);
  // this lane's two B-frag row pointers (rows wid*32 + {0,16} + l16), d-offset l4*8
  const float* xp0 = x + ((size_t)s * NROW + row0 + wid * 32 + l16) * DD + l4 * 8;
  const float* xp1 = xp0 + 16 * DD;

  const f32x4 zero = {0.f, 0.f, 0.f, 0.f};
  f32x4 acc[4][2];
#pragma unroll
  for (int m = 0; m < 4; ++m)
#pragma unroll
    for (int n = 0; n < 2; ++n) acc[m][n] = zero;

  f32x4 xpre[2][2][2];                 // [nn][k2][half] in-flight x (32 VGPR)
  V8 bf2[2][2];                        // current-step bf16 B-frags

  auto STAGEW1 = [&](int kc, int p) {
    const char* wsrc = w1b + (size_t)kc * 8192;
    char* wdst = (char*)w1s[p] + (wid << 10);
#pragma unroll
    for (int r = 0; r < 2; ++r)
      gload_lds16(wsrc + r * 4096 + tid * 16, wdst + r * 4096);
  };

  auto LOADX = [&](int kc) {
#pragma unroll
    for (int nn = 0; nn < 2; ++nn) {
      const float* rp = (nn ? xp1 : xp0) + kc * 64;
#pragma unroll
      for (int k2 = 0; k2 < 2; ++k2) {
        xpre[nn][k2][0] = *(const f32x4*)(rp + k2 * 32);
        xpre[nn][k2][1] = *(const f32x4*)(rp + k2 * 32 + 4);
      }
    }
  };

  auto CVT = [&]() {                   // xpre (f32) -> bf2 (bf16x8), v_cvt_pk
#pragma unroll
    for (int nn = 0; nn < 2; ++nn)
#pragma unroll
      for (int k2 = 0; k2 < 2; ++k2) {
        bf16x8 v;
#pragma unroll
        for (int r = 0; r < 4; ++r) {
          v[r]     = (__bf16)xpre[nn][k2][0][r];
          v[r + 4] = (__bf16)xpre[nn][k2][1][r];
        }
        bf2[nn][k2].b = v;
      }
  };

  auto COMPUTE = [&](int p) {
    V8 af[4][2];
#pragma unroll
    for (int mm = 0; mm < 4; ++mm)
#pragma unroll
      for (int k2 = 0; k2 < 2; ++k2) {
        int rl = mm * 16 + l16;
        af[mm][k2].s = *(const short8v*)((const char*)w1s[p] +
                         ((rl * 128 + k2 * 64 + l4 * 16) ^ ((rl & 7) << 4)));
      }
#pragma unroll
    for (int k2 = 0; k2 < 2; ++k2)
#pragma unroll
      for (int mm = 0; mm < 4; ++mm)
#pragma unroll
        for (int nn = 0; nn < 2; ++nn)
          acc[mm][nn] = __builtin_amdgcn_mfma_f32_16x16x32_bf16(af[mm][k2].b, bf2[nn][k2].b,
                                                                acc[mm][nn], 0, 0, 0);
  };

  STAGEW1(0, 0);
  LOADX(0);
  __syncthreads();                     // w1s[0] ready (drains gloads)
  int p = 0;
  for (int kc = 0; kc < 12; ++kc) {
    CVT();                             // consume xpre -> bf2 (frees xpre for prefetch)
    if (kc < 11) { STAGEW1(kc + 1, p ^ 1); LOADX(kc + 1); }
    COMPUTE(p);                        // prefetch latency hides under MFMAs
    __syncthreads();
    p ^= 1;
  }

  // epilogue: +b1, gelu, store bf16 into blocked PRE-SWIZZLED H (for chiB's gload_lds)
  unsigned short* Hb = H + ((size_t)pr * 128 + rb) * 8192;
#pragma unroll
  for (int mm = 0; mm < 4; ++mm) {
    f32x4 bv = *(const f32x4*)(b1 + (size_t)pr * KK + mm * 16 + l4 * 4);
#pragma unroll
    for (int nn = 0; nn < 2; ++nn) {
      union { short4v s4; __bf16 b4[4]; } o;
#pragma unroll
      for (int r = 0; r < 4; ++r) o.b4[r] = (__bf16)gelu_t(acc[mm][nn][r] + bv[r]);
      int rl = wid * 32 + nn * 16 + l16;
      *(short4v*)((char*)Hb + ((rl * 128 + mm * 32 + l4 * 8) ^ ((rl & 7) << 4))) = o.s4;
    }
  }
}

// ---- Phase B: out[t] = x[t] + sum_s H[s,t](128xK) * W2P[t,s](Kx128) + b2sum[t]
// H staged via global_load_lds (already swizzled), double-buffered over the s-loop,
// one barrier per source. W2 A-frags direct from L2-resident W2P. Swapped operands
// so D-frag regs run along out-columns -> coalesced f32x4 stores.
__global__ __launch_bounds__(256, 5)
void chiB(const unsigned short* __restrict__ H, const float* __restrict__ x,
          const float* __restrict__ M, const unsigned short* __restrict__ W2P,
          const float* __restrict__ b2sum, float* __restrict__ out) {
  __shared__ __align__(16) unsigned short hs[2][128 * 64];   // 2 x 16 KB, swizzled [row][k]

  int bid = (int)blockIdx.x;
  int nid = (bid & 7) * 672 + (bid >> 3);   // 5376 = 8*672; nb innermost -> L2 reuse of H chunk
  int nb = nid % 6, rem = nid / 6;
  int rb = rem % 128, t = rem / 128;
  int row0 = rb * 128, col0 = nb * 128;

  int tid = (int)threadIdx.x;
  int wid = tid >> 6, lane = tid & 63, l16 = lane & 15, l4 = lane >> 4;
  int wr = wid & 1, wc = wid >> 1;          // wave = 64 rows x 64 cols of the 128x128 tile

  // active-source list, 3 bits per entry
  unsigned spack = 0; int nact = 0;
  for (int s = 0; s < NH; ++s) {
    if (s == t) continue;
    if (fabsf(M[s * NH + t]) > THRG) { spack |= (unsigned)s << (3 * nact); ++nact; }
  }

  const f32x4 zero = {0.f, 0.f, 0.f, 0.f};
  f32x4 acc[4][4];
#pragma unroll
  for (int m = 0; m < 4; ++m)
#pragma unroll
    for (int n = 0; n < 4; ++n) acc[m][n] = zero;

  auto GLOADH = [&](int s, int p) {
    const char* src = (const char*)H + ((size_t)(s * NH + t) * 128 + rb) * 16384;
    char* dst = (char*)hs[p] + (wid << 10);
#pragma unroll
    for (int r = 0; r < 4; ++r)
      gload_lds16(src + r * 4096 + tid * 16, dst + r * 4096);
  };

  if (nact > 0) {
    GLOADH(spack & 7, 0);
    int p = 0;
    for (int i = 0; i < nact; ++i) {
      __syncthreads();                         // vmcnt(0) drain: hs[p] ready
      if (i + 1 < nact) GLOADH((spack >> (3 * (i + 1))) & 7, p ^ 1);
      int s = (spack >> (3 * i)) & 7;
      const char* wp = (const char*)(W2P + ((size_t)(t * NH + s) * DD + col0 + wc * 64) * KK);
      V8 af[4][2], bfr[4][2];
#pragma unroll
      for (int m = 0; m < 4; ++m)
#pragma unroll
        for (int k2 = 0; k2 < 2; ++k2)
          af[m][k2].s = *(const short8v*)(wp + (((m * 16 + l16) * 64 + k2 * 32 + l4 * 8) * 2));
#pragma unroll
      for (int n = 0; n < 4; ++n)
#pragma unroll
        for (int k2 = 0; k2 < 2; ++k2) {
          int rl = wr * 64 + n * 16 + l16;
          bfr[n][k2].s = *(const short8v*)((const char*)hs[p] +
                           ((rl * 128 + k2 * 64 + l4 * 16) ^ ((rl & 7) << 4)));
        }
#pragma unroll
      for (int k2 = 0; k2 < 2; ++k2)
#pragma unroll
        for (int m = 0; m < 4; ++m)
#pragma unroll
          for (int n = 0; n < 4; ++n)
            acc[m][n] = __builtin_amdgcn_mfma_f32_16x16x32_bf16(af[m][k2].b, bfr[n][k2].b,
                                                                acc[m][n], 0, 0, 0);
      p ^= 1;
    }
  }

  // epilogue: + x residual (exact f32) + b2sum; coalesced f32x4 stores along cols
#pragma unroll
  for (int m = 0; m < 4; ++m) {
    int col = col0 + wc * 64 + m * 16 + l4 * 4;
    f32x4 bv = *(const f32x4*)(b2sum + (size_t)t * DD + col);
#pragma unroll
    for (int n = 0; n < 4; ++n) {
      int row = row0 + wr * 64 + n * 16 + l16;
      size_t off = ((size_t)t * NROW + row) * DD + col;
      f32x4 xv = *(const f32x4*)(x + off);
      f32x4 ov;
#pragma unroll
      for (int r = 0; r < 4; ++r) ov[r] = acc[m][n][r] + xv[r] + bv[r];
      *(f32x4*)(out + off) = ov;
    }
  }
}

extern "C" void kernel_launch(void* const* d_in, const int* in_sizes, int n_in,
                              void* d_out, int out_size, void* d_ws, size_t ws_size,
                              hipStream_t stream) {
  const float* x  = (const float*)d_in[0];
  const float* M  = (const float*)d_in[1];
  const float* W1 = (const float*)d_in[2];
  const float* b1 = (const float*)d_in[3];
  const float* W2 = (const float*)d_in[4];
  const float* b2 = (const float*)d_in[5];
  float* out = (float*)d_out;

  char* ws = (char*)d_ws;
  unsigned short* W1P = (unsigned short*)ws;                         // 4,816,896 B
  unsigned short* W2P = (unsigned short*)(ws + 4816896);             // 4,816,896 B
  float* b2sum        = (float*)(ws + 9633792);                      // 21,504 B
  unsigned short* H   = (unsigned short*)(ws + 9655296);             // 102,760,448 B (blocked)

  prep_w1<<<dim3(49), dim3(256), 0, stream>>>(W1, W1P);
  prep_w2<<<dim3(49), dim3(256), 0, stream>>>(M, W2, W2P);
  prep_b2<<<dim3((NH * DD + 255) / 256), dim3(256), 0, stream>>>(M, b2, b2sum);
  chiA<<<dim3(128 * 49), dim3(256), 0, stream>>>(x, M, W1P, b1, H);
  chiB<<<dim3(NH * 128 * 6), dim3(256), 0, stream>>>(H, x, M, W2P, b2sum, out);
}

// Round 4
// 651.768 us; speedup vs baseline: 1.0899x; 1.0899x over previous
//
#include <hip/hip_runtime.h>
#include <hip/hip_bf16.h>
#include <math.h>

// Problem constants
#define NH   7        // hazards
#define NROW 16384    // B*S = 8*2048
#define DD   768      // hidden dim
#define KK   64       // bottleneck dim
#define THRG 0.05f

typedef float  f32x4   __attribute__((ext_vector_type(4)));
typedef __bf16 bf16x8  __attribute__((ext_vector_type(8)));
typedef short  short8v __attribute__((ext_vector_type(8)));
typedef short  short4v __attribute__((ext_vector_type(4)));

union V8 { short8v s; bf16x8 b; };

__device__ __forceinline__ unsigned short f2bf(float f) {
  unsigned u = __float_as_uint(f);
  u = (u + 0x7FFFu + ((u >> 16) & 1u)) >> 16;   // round-to-nearest-even
  return (unsigned short)u;
}

__device__ __forceinline__ float gate_of(const float* __restrict__ M, int s, int t) {
  float m = M[s * NH + t];
  return (s != t && fabsf(m) > THRG) ? m : 0.0f;
}

__device__ __forceinline__ float gelu_t(float v) {
  float u = 0.7978845608028654f * (v + 0.044715f * v * v * v);
  return v / (1.0f + __expf(-2.0f * u));   // v * sigmoid(2u)
}

// ---- prep: W1 [s][t][d][k] f32 -> W1P [pr][kc][kcol(64)][dl(64)] bf16 (d contiguous per kcol row)
__global__ void prep_w1(const float* __restrict__ W1, unsigned short* __restrict__ W1P) {
  int pr = blockIdx.x;                       // pr = s*7+t
  const float* src = W1 + (size_t)pr * DD * KK;
  unsigned short* dst = W1P + (size_t)pr * 12 * 4096;
  for (int idx = threadIdx.x; idx < 12 * 64 * 64; idx += blockDim.x) {
    int kc = idx >> 12, rem = idx & 4095;
    int kcol = rem >> 6, dl = rem & 63;
    dst[idx] = f2bf(src[(size_t)(kc * 64 + dl) * KK + kcol]);
  }
}

// ---- prep: W2 [s][t][k][d] f32 -> W2P [(t*7+s)*6+nb][dloc(128)][k(64)] bf16, gate folded
__global__ void prep_w2(const float* __restrict__ M, const float* __restrict__ W2,
                        unsigned short* __restrict__ W2P) {
  int st = blockIdx.x;                       // st = s*7+t
  int s = st / NH, t = st % NH;
  float g = gate_of(M, s, t);
  const float* src = W2 + (size_t)st * KK * DD;
  unsigned short* dst = W2P + (size_t)((t * NH + s) * 6) * 8192;
  for (int idx = threadIdx.x; idx < 6 * 128 * 64; idx += blockDim.x) {
    int nb = idx >> 13, rem = idx & 8191;
    int dloc = rem >> 6, k = rem & 63;
    dst[idx] = f2bf(g * src[(size_t)k * DD + nb * 128 + dloc]);
  }
}

// ---- prep: b2sum[t][d] = sum_s gate(s,t) * b2[s][t][d]
__global__ void prep_b2(const float* __restrict__ M, const float* __restrict__ b2,
                        float* __restrict__ b2sum) {
  int idx = blockIdx.x * blockDim.x + threadIdx.x;
  if (idx >= NH * DD) return;
  int t = idx / DD, d = idx % DD;
  float acc = 0.f;
  for (int s = 0; s < NH; ++s)
    acc += gate_of(M, s, t) * b2[(size_t)(s * NH + t) * DD + d];
  b2sum[idx] = acc;
}

// ---- Phase A: H[pr][row][kcol] = gelu(x[s] W1[s,t] + b1)  (bf16, gate NOT applied)
// Identical to the 244 us baseline except occupancy: 24 KB LDS + 52 VGPR permit
// 6 blocks/CU, not 3 — inter-block TLP is what hides the 2-barrier staging latency.
__global__ __launch_bounds__(256, 6)
void chiA(const float* __restrict__ x, const float* __restrict__ M,
          const unsigned short* __restrict__ W1P, const float* __restrict__ b1,
          unsigned short* __restrict__ H) {
  __shared__ __align__(16) unsigned short xs[128 * 64];   // 16 KB, swizzled [xrow][d]
  __shared__ __align__(16) unsigned short w1s[64 * 64];   //  8 KB, swizzled [kcol][d]

  int bid = (int)blockIdx.x;
  int nid = (bid & 7) * 784 + (bid >> 3);   // 6272 = 8*784; t innermost -> L2 reuse of x chunk
  int rb = nid / 49, pr = nid % 49;
  int s = pr / NH, t = pr % NH;
  if (gate_of(M, s, t) == 0.0f) return;
  int row0 = rb * 128;

  int tid = (int)threadIdx.x;
  int wid = tid >> 6, lane = tid & 63, l16 = lane & 15, l4 = lane >> 4;

  const f32x4 zero = {0.f, 0.f, 0.f, 0.f};
  f32x4 acc[4][2];
#pragma unroll
  for (int m = 0; m < 4; ++m)
#pragma unroll
    for (int n = 0; n < 2; ++n) acc[m][n] = zero;

  const float* xb = x + ((size_t)s * NROW + row0) * DD;
  const unsigned short* w1b = W1P + (size_t)pr * 12 * 4096;

  for (int kc = 0; kc < 12; ++kc) {
    __syncthreads();   // protect LDS from previous step's readers
    // stage x chunk [128 rows][64 d] f32 -> bf16 swizzled
#pragma unroll
    for (int r = 0; r < 4; ++r) {
      int L = r * 4096 + tid * 16;          // byte offset in chunk
      int row = L >> 7, colB = L & 127;     // col = colB/2 (elems)
      const float* gp = xb + (size_t)row * DD + kc * 64 + (colB >> 1);
      f32x4 v0 = *(const f32x4*)gp;
      f32x4 v1 = *(const f32x4*)(gp + 4);
      short8v sv;
      sv[0] = (short)f2bf(v0[0]); sv[1] = (short)f2bf(v0[1]);
      sv[2] = (short)f2bf(v0[2]); sv[3] = (short)f2bf(v0[3]);
      sv[4] = (short)f2bf(v1[0]); sv[5] = (short)f2bf(v1[1]);
      sv[6] = (short)f2bf(v1[2]); sv[7] = (short)f2bf(v1[3]);
      *(short8v*)((char*)xs + (L ^ ((row & 7) << 4))) = sv;
    }
    // stage W1 chunk [64 kcol][64 d] (8 KB), plain copy with swizzle
#pragma unroll
    for (int r = 0; r < 2; ++r) {
      int L = r * 4096 + tid * 16;
      int row = L >> 7;
      short8v v = *(const short8v*)((const char*)w1b + (size_t)kc * 8192 + L);
      *(short8v*)((char*)w1s + (L ^ ((row & 7) << 4))) = v;
    }
    __syncthreads();

    V8 af[4][2], bf2[2][2];
#pragma unroll
    for (int mm = 0; mm < 4; ++mm)
#pragma unroll
      for (int k2 = 0; k2 < 2; ++k2) {
        int rowl = mm * 16 + l16;
        int byte = (rowl * 128 + k2 * 64 + l4 * 16) ^ ((rowl & 7) << 4);
        af[mm][k2].s = *(const short8v*)((const char*)w1s + byte);
      }
#pragma unroll
    for (int nn = 0; nn < 2; ++nn)
#pragma unroll
      for (int k2 = 0; k2 < 2; ++k2) {
        int xr = wid * 32 + nn * 16 + l16;
        int byte = (xr * 128 + k2 * 64 + l4 * 16) ^ ((xr & 7) << 4);
        bf2[nn][k2].s = *(const short8v*)((const char*)xs + byte);
      }
#pragma unroll
    for (int k2 = 0; k2 < 2; ++k2)
#pragma unroll
      for (int mm = 0; mm < 4; ++mm)
#pragma unroll
        for (int nn = 0; nn < 2; ++nn)
          acc[mm][nn] = __builtin_amdgcn_mfma_f32_16x16x32_bf16(af[mm][k2].b, bf2[nn][k2].b, acc[mm][nn], 0, 0, 0);
  }

  // epilogue: +b1, gelu, store bf16 H (contiguous short4 along kcol)
#pragma unroll
  for (int mm = 0; mm < 4; ++mm) {
    f32x4 bv = *(const f32x4*)(b1 + (size_t)pr * KK + mm * 16 + l4 * 4);
#pragma unroll
    for (int nn = 0; nn < 2; ++nn) {
      short4v o;
#pragma unroll
      for (int r = 0; r < 4; ++r) o[r] = (short)f2bf(gelu_t(acc[mm][nn][r] + bv[r]));
      int xrow = row0 + wid * 32 + nn * 16 + l16;
      unsigned short* hp = H + ((size_t)pr * NROW + xrow) * KK + mm * 16 + l4 * 4;
      *(short4v*)hp = o;
    }
  }
}

// ---- Phase B: out[t] = x[t] + sum_s H[s,t](128xK) * W2P[t,s](Kx128) + b2sum[t]
// Baseline staging (hs + w2s in LDS, 2 barriers/source) but SWAPPED operands:
// A = w2s (dloc rows), B = hs (x rows) so the D-frag's 4 regs run along output
// columns -> coalesced f32x4 residual loads + stores. Occupancy 3 -> 4 blocks/CU.
__global__ __launch_bounds__(256, 4)
void chiB(const unsigned short* __restrict__ H, const float* __restrict__ x,
          const float* __restrict__ M, const unsigned short* __restrict__ W2P,
          const float* __restrict__ b2sum, float* __restrict__ out) {
  __shared__ __align__(16) unsigned short hs[128 * 64];   // 16 KB, swizzled [row][k]
  __shared__ __align__(16) unsigned short w2s[128 * 64];  // 16 KB, swizzled [dloc][k]

  int bid = (int)blockIdx.x;
  int nid = (bid & 7) * 672 + (bid >> 3);   // 5376 = 8*672; nb innermost -> L2 reuse of H chunk
  int nb = nid % 6, rem = nid / 6;
  int rb = rem % 128, t = rem / 128;
  int row0 = rb * 128, col0 = nb * 128;

  int tid = (int)threadIdx.x;
  int wid = tid >> 6, lane = tid & 63, l16 = lane & 15, l4 = lane >> 4;
  int wr = wid & 1, wc = wid >> 1;          // wave = 64 rows x 64 cols of the 128x128 tile

  const f32x4 zero = {0.f, 0.f, 0.f, 0.f};
  f32x4 acc[4][4];                          // [m]=col tiles, [n]=row tiles
#pragma unroll
  for (int m = 0; m < 4; ++m)
#pragma unroll
    for (int n = 0; n < 4; ++n) acc[m][n] = zero;

  for (int s = 0; s < NH; ++s) {
    if (gate_of(M, s, t) == 0.0f) continue;
    __syncthreads();   // protect LDS from previous step's readers
    const char* hb = (const char*)(H + ((size_t)(s * NH + t) * NROW + row0) * KK);
    const char* wb = (const char*)(W2P + (size_t)((t * NH + s) * 6 + nb) * 8192);
#pragma unroll
    for (int r = 0; r < 4; ++r) {
      int L = r * 4096 + tid * 16;
      int row = L >> 7;
      short8v v = *(const short8v*)(hb + L);
      *(short8v*)((char*)hs + (L ^ ((row & 7) << 4))) = v;
      short8v w = *(const short8v*)(wb + L);
      *(short8v*)((char*)w2s + (L ^ ((row & 7) << 4))) = w;
    }
    __syncthreads();

    V8 af[4][2], bfr[4][2];
#pragma unroll
    for (int m = 0; m < 4; ++m)                 // A: W2 dloc rows (output columns)
#pragma unroll
      for (int k2 = 0; k2 < 2; ++k2) {
        int dl = wc * 64 + m * 16 + l16;
        int byte = (dl * 128 + k2 * 64 + l4 * 16) ^ ((dl & 7) << 4);
        af[m][k2].s = *(const short8v*)((const char*)w2s + byte);
      }
#pragma unroll
    for (int n = 0; n < 4; ++n)                 // B: H rows (output rows)
#pragma unroll
      for (int k2 = 0; k2 < 2; ++k2) {
        int rl = wr * 64 + n * 16 + l16;
        int byte = (rl * 128 + k2 * 64 + l4 * 16) ^ ((rl & 7) << 4);
        bfr[n][k2].s = *(const short8v*)((const char*)hs + byte);
      }
#pragma unroll
    for (int k2 = 0; k2 < 2; ++k2)
#pragma unroll
      for (int m = 0; m < 4; ++m)
#pragma unroll
        for (int n = 0; n < 4; ++n)
          acc[m][n] = __builtin_amdgcn_mfma_f32_16x16x32_bf16(af[m][k2].b, bfr[n][k2].b, acc[m][n], 0, 0, 0);
  }

  // epilogue: + x residual (exact f32) + b2sum; coalesced f32x4 along columns
#pragma unroll
  for (int m = 0; m < 4; ++m) {
    int col = col0 + wc * 64 + m * 16 + l4 * 4;
    f32x4 bv = *(const f32x4*)(b2sum + (size_t)t * DD + col);
#pragma unroll
    for (int n = 0; n < 4; ++n) {
      int row = row0 + wr * 64 + n * 16 + l16;
      size_t off = ((size_t)t * NROW + row) * DD + col;
      f32x4 xv = *(const f32x4*)(x + off);
      f32x4 ov;
#pragma unroll
      for (int r = 0; r < 4; ++r) ov[r] = acc[m][n][r] + xv[r] + bv[r];
      *(f32x4*)(out + off) = ov;
    }
  }
}

extern "C" void kernel_launch(void* const* d_in, const int* in_sizes, int n_in,
                              void* d_out, int out_size, void* d_ws, size_t ws_size,
                              hipStream_t stream) {
  const float* x  = (const float*)d_in[0];
  const float* M  = (const float*)d_in[1];
  const float* W1 = (const float*)d_in[2];
  const float* b1 = (const float*)d_in[3];
  const float* W2 = (const float*)d_in[4];
  const float* b2 = (const float*)d_in[5];
  float* out = (float*)d_out;

  char* ws = (char*)d_ws;
  unsigned short* W1P = (unsigned short*)ws;                         // 4,816,896 B
  unsigned short* W2P = (unsigned short*)(ws + 4816896);             // 4,816,896 B
  float* b2sum        = (float*)(ws + 9633792);                      // 21,504 B
  unsigned short* H   = (unsigned short*)(ws + 9655296);             // 102,760,448 B

  prep_w1<<<dim3(49), dim3(256), 0, stream>>>(W1, W1P);
  prep_w2<<<dim3(49), dim3(256), 0, stream>>>(M, W2, W2P);
  prep_b2<<<dim3((NH * DD + 255) / 256), dim3(256), 0, stream>>>(M, b2, b2sum);
  chiA<<<dim3(128 * 49), dim3(256), 0, stream>>>(x, M, W1P, b1, H);
  chiB<<<dim3(NH * 128 * 6), dim3(256), 0, stream>>>(H, x, M, W2P, b2sum, out);
}

// Round 5
// 636.609 us; speedup vs baseline: 1.1159x; 1.0238x over previous
//
#include <hip/hip_runtime.h>
#include <hip/hip_bf16.h>
#include <math.h>

// Problem constants
#define NH   7        // hazards
#define NROW 16384    // B*S = 8*2048
#define DD   768      // hidden dim
#define KK   64       // bottleneck dim
#define THRG 0.05f

typedef float  f32x4   __attribute__((ext_vector_type(4)));
typedef __bf16 bf16x8  __attribute__((ext_vector_type(8)));
typedef short  short8v __attribute__((ext_vector_type(8)));
typedef short  short4v __attribute__((ext_vector_type(4)));

union V8 { short8v s; bf16x8 b; };

__device__ __forceinline__ unsigned short f2bf(float f) {
  unsigned u = __float_as_uint(f);
  u = (u + 0x7FFFu + ((u >> 16) & 1u)) >> 16;   // round-to-nearest-even
  return (unsigned short)u;
}

__device__ __forceinline__ float gate_of(const float* __restrict__ M, int s, int t) {
  float m = M[s * NH + t];
  return (s != t && fabsf(m) > THRG) ? m : 0.0f;
}

__device__ __forceinline__ float gelu_t(float v) {
  float u = 0.7978845608028654f * (v + 0.044715f * v * v * v);
  return v / (1.0f + __expf(-2.0f * u));   // v * sigmoid(2u)
}

// ---- prep: W1 [s][t][d][k] f32 -> W1P [pr][kc][kcol(64)][dl(64)] bf16 (d contiguous per kcol row)
__global__ void prep_w1(const float* __restrict__ W1, unsigned short* __restrict__ W1P) {
  int pr = blockIdx.x;                       // pr = s*7+t
  const float* src = W1 + (size_t)pr * DD * KK;
  unsigned short* dst = W1P + (size_t)pr * 12 * 4096;
  for (int idx = threadIdx.x; idx < 12 * 64 * 64; idx += blockDim.x) {
    int kc = idx >> 12, rem = idx & 4095;
    int kcol = rem >> 6, dl = rem & 63;
    dst[idx] = f2bf(src[(size_t)(kc * 64 + dl) * KK + kcol]);
  }
}

// ---- prep: W2 [s][t][k][d] f32 -> W2P [t][s][d(768)][k(64)] bf16, gate folded.
// chiB reads A-fragments directly from this (L2-resident), no LDS staging.
__global__ void prep_w2(const float* __restrict__ M, const float* __restrict__ W2,
                        unsigned short* __restrict__ W2P) {
  int st = blockIdx.x;                       // st = s*7+t
  int s = st / NH, t = st % NH;
  float g = gate_of(M, s, t);
  const float* src = W2 + (size_t)st * KK * DD;
  unsigned short* dst = W2P + (size_t)(t * NH + s) * DD * KK;
  for (int idx = threadIdx.x; idx < DD * KK; idx += blockDim.x) {
    int d = idx >> 6, k = idx & 63;
    dst[idx] = f2bf(g * src[(size_t)k * DD + d]);
  }
}

// ---- prep: b2sum[t][d] = sum_s gate(s,t) * b2[s][t][d]
__global__ void prep_b2(const float* __restrict__ M, const float* __restrict__ b2,
                        float* __restrict__ b2sum) {
  int idx = blockIdx.x * blockDim.x + threadIdx.x;
  if (idx >= NH * DD) return;
  int t = idx / DD, d = idx % DD;
  float acc = 0.f;
  for (int s = 0; s < NH; ++s)
    acc += gate_of(M, s, t) * b2[(size_t)(s * NH + t) * DD + d];
  b2sum[idx] = acc;
}

// ---- Phase A: H[pr][row][kcol] = gelu(x[s] W1[s,t] + b1)  (bf16, gate NOT applied)
// BYTE-IDENTICAL to the 488-baseline version (244 us measured, occ 40%).
__global__ __launch_bounds__(256, 3)
void chiA(const float* __restrict__ x, const float* __restrict__ M,
          const unsigned short* __restrict__ W1P, const float* __restrict__ b1,
          unsigned short* __restrict__ H) {
  __shared__ __align__(16) unsigned short xs[128 * 64];   // 16 KB, swizzled [xrow][d]
  __shared__ __align__(16) unsigned short w1s[64 * 64];   //  8 KB, swizzled [kcol][d]

  int bid = (int)blockIdx.x;
  int nid = (bid & 7) * 784 + (bid >> 3);   // 6272 = 8*784; t innermost -> L2 reuse of x chunk
  int rb = nid / 49, pr = nid % 49;
  int s = pr / NH, t = pr % NH;
  if (gate_of(M, s, t) == 0.0f) return;
  int row0 = rb * 128;

  int tid = (int)threadIdx.x;
  int wid = tid >> 6, lane = tid & 63, l16 = lane & 15, l4 = lane >> 4;

  const f32x4 zero = {0.f, 0.f, 0.f, 0.f};
  f32x4 acc[4][2];
#pragma unroll
  for (int m = 0; m < 4; ++m)
#pragma unroll
    for (int n = 0; n < 2; ++n) acc[m][n] = zero;

  const float* xb = x + ((size_t)s * NROW + row0) * DD;
  const unsigned short* w1b = W1P + (size_t)pr * 12 * 4096;

  for (int kc = 0; kc < 12; ++kc) {
    __syncthreads();   // protect LDS from previous step's readers
    // stage x chunk [128 rows][64 d] f32 -> bf16 swizzled
#pragma unroll
    for (int r = 0; r < 4; ++r) {
      int L = r * 4096 + tid * 16;          // byte offset in chunk
      int row = L >> 7, colB = L & 127;     // col = colB/2 (elems)
      const float* gp = xb + (size_t)row * DD + kc * 64 + (colB >> 1);
      f32x4 v0 = *(const f32x4*)gp;
      f32x4 v1 = *(const f32x4*)(gp + 4);
      short8v sv;
      sv[0] = (short)f2bf(v0[0]); sv[1] = (short)f2bf(v0[1]);
      sv[2] = (short)f2bf(v0[2]); sv[3] = (short)f2bf(v0[3]);
      sv[4] = (short)f2bf(v1[0]); sv[5] = (short)f2bf(v1[1]);
      sv[6] = (short)f2bf(v1[2]); sv[7] = (short)f2bf(v1[3]);
      *(short8v*)((char*)xs + (L ^ ((row & 7) << 4))) = sv;
    }
    // stage W1 chunk [64 kcol][64 d] (8 KB), plain copy with swizzle
#pragma unroll
    for (int r = 0; r < 2; ++r) {
      int L = r * 4096 + tid * 16;
      int row = L >> 7;
      short8v v = *(const short8v*)((const char*)w1b + (size_t)kc * 8192 + L);
      *(short8v*)((char*)w1s + (L ^ ((row & 7) << 4))) = v;
    }
    __syncthreads();

    V8 af[4][2], bf2[2][2];
#pragma unroll
    for (int mm = 0; mm < 4; ++mm)
#pragma unroll
      for (int k2 = 0; k2 < 2; ++k2) {
        int rowl = mm * 16 + l16;
        int byte = (rowl * 128 + k2 * 64 + l4 * 16) ^ ((rowl & 7) << 4);
        af[mm][k2].s = *(const short8v*)((const char*)w1s + byte);
      }
#pragma unroll
    for (int nn = 0; nn < 2; ++nn)
#pragma unroll
      for (int k2 = 0; k2 < 2; ++k2) {
        int xr = wid * 32 + nn * 16 + l16;
        int byte = (xr * 128 + k2 * 64 + l4 * 16) ^ ((xr & 7) << 4);
        bf2[nn][k2].s = *(const short8v*)((const char*)xs + byte);
      }
#pragma unroll
    for (int k2 = 0; k2 < 2; ++k2)
#pragma unroll
      for (int mm = 0; mm < 4; ++mm)
#pragma unroll
        for (int nn = 0; nn < 2; ++nn)
          acc[mm][nn] = __builtin_amdgcn_mfma_f32_16x16x32_bf16(af[mm][k2].b, bf2[nn][k2].b, acc[mm][nn], 0, 0, 0);
  }

  // epilogue: +b1, gelu, store bf16 H (contiguous short4 along kcol)
#pragma unroll
  for (int mm = 0; mm < 4; ++mm) {
    f32x4 bv = *(const f32x4*)(b1 + (size_t)pr * KK + mm * 16 + l4 * 4);
#pragma unroll
    for (int nn = 0; nn < 2; ++nn) {
      short4v o;
#pragma unroll
      for (int r = 0; r < 4; ++r) o[r] = (short)f2bf(gelu_t(acc[mm][nn][r] + bv[r]));
      int xrow = row0 + wid * 32 + nn * 16 + l16;
      unsigned short* hp = H + ((size_t)pr * NROW + xrow) * KK + mm * 16 + l4 * 4;
      *(short4v*)hp = o;
    }
  }
}

// ---- Phase B: out[t] = x[t] + sum_s H[s,t](32xK) * W2P[t,s](Kx384) + b2sum[t]
// Block = 32 rows x 384 cols, one t. Per s-step: stage 4 KB of H (16 B/thread),
// read W2 A-frags DIRECTLY from L2-resident W2P (no w2s LDS), 24 MFMA/wave.
// H read ~once from HBM (no 6x col-block re-read). D-frag runs along output
// columns -> coalesced f32x4 residual loads + stores (layout verified in R4).
__global__ __launch_bounds__(256, 4)
void chiB(const unsigned short* __restrict__ H, const float* __restrict__ x,
          const float* __restrict__ M, const unsigned short* __restrict__ W2P,
          const float* __restrict__ b2sum, float* __restrict__ out) {
  __shared__ __align__(16) unsigned short hs[32 * 64];    // 4 KB, swizzled [row][k]

  int bid = (int)blockIdx.x;
  int nid = (bid & 7) * 896 + (bid >> 3);   // 7168 = 8*896; rb/cb innermost -> W2P[t] stays in XCD L2
  int t = nid >> 10;                        // nid / 1024
  int rem = nid & 1023;
  int rb = rem >> 1, cb = rem & 1;
  int row0 = rb * 32, col0 = cb * 384;

  int tid = (int)threadIdx.x;
  int wid = tid >> 6, lane = tid & 63, l16 = lane & 15, l4 = lane >> 4;
  int wcol0 = col0 + wid * 96;              // each wave owns 96 output cols

  const f32x4 zero = {0.f, 0.f, 0.f, 0.f};
  f32x4 acc[6][2];                          // [m]=col frags (6x16=96), [n]=row frags (2x16=32)
#pragma unroll
  for (int m = 0; m < 6; ++m)
#pragma unroll
    for (int n = 0; n < 2; ++n) acc[m][n] = zero;

  for (int s = 0; s < NH; ++s) {
    if (gate_of(M, s, t) == 0.0f) continue;
    __syncthreads();   // protect hs from previous step's readers
    {  // stage H chunk [32 rows][64 k] = 4 KB, 16 B/thread, swizzled
      const char* hb = (const char*)(H + ((size_t)(s * NH + t) * NROW + row0) * KK);
      int L = tid * 16;
      int row = L >> 7;
      short8v v = *(const short8v*)(hb + L);
      *(short8v*)((char*)hs + (L ^ ((row & 7) << 4))) = v;
    }
    __syncthreads();

    V8 bfr[2][2];
#pragma unroll
    for (int n = 0; n < 2; ++n)               // B: H rows (output rows)
#pragma unroll
      for (int k2 = 0; k2 < 2; ++k2) {
        int rl = n * 16 + l16;
        int byte = (rl * 128 + k2 * 64 + l4 * 16) ^ ((rl & 7) << 4);
        bfr[n][k2].s = *(const short8v*)((const char*)hs + byte);
      }

    const char* wp = (const char*)(W2P + ((size_t)(t * NH + s) * DD + wcol0) * KK);
    V8 af[6][2];
#pragma unroll
    for (int m = 0; m < 6; ++m)               // A: W2 d-rows (output cols), direct from L2
#pragma unroll
      for (int k2 = 0; k2 < 2; ++k2)
        af[m][k2].s = *(const short8v*)(wp + (m * 16 + l16) * 128 + k2 * 64 + l4 * 16);

#pragma unroll
    for (int k2 = 0; k2 < 2; ++k2)
#pragma unroll
      for (int m = 0; m < 6; ++m)
#pragma unroll
        for (int n = 0; n < 2; ++n)
          acc[m][n] = __builtin_amdgcn_mfma_f32_16x16x32_bf16(af[m][k2].b, bfr[n][k2].b, acc[m][n], 0, 0, 0);
  }

  // epilogue: + x residual (exact f32) + b2sum; coalesced f32x4 along columns
#pragma unroll
  for (int m = 0; m < 6; ++m) {
    int col = wcol0 + m * 16 + l4 * 4;
    f32x4 bv = *(const f32x4*)(b2sum + (size_t)t * DD + col);
#pragma unroll
    for (int n = 0; n < 2; ++n) {
      int row = row0 + n * 16 + l16;
      size_t off = ((size_t)t * NROW + row) * DD + col;
      f32x4 xv = *(const f32x4*)(x + off);
      f32x4 ov;
#pragma unroll
      for (int r = 0; r < 4; ++r) ov[r] = acc[m][n][r] + xv[r] + bv[r];
      *(f32x4*)(out + off) = ov;
    }
  }
}

extern "C" void kernel_launch(void* const* d_in, const int* in_sizes, int n_in,
                              void* d_out, int out_size, void* d_ws, size_t ws_size,
                              hipStream_t stream) {
  const float* x  = (const float*)d_in[0];
  const float* M  = (const float*)d_in[1];
  const float* W1 = (const float*)d_in[2];
  const float* b1 = (const float*)d_in[3];
  const float* W2 = (const float*)d_in[4];
  const float* b2 = (const float*)d_in[5];
  float* out = (float*)d_out;

  char* ws = (char*)d_ws;
  unsigned short* W1P = (unsigned short*)ws;                         // 4,816,896 B
  unsigned short* W2P = (unsigned short*)(ws + 4816896);             // 4,816,896 B
  float* b2sum        = (float*)(ws + 9633792);                      // 21,504 B
  unsigned short* H   = (unsigned short*)(ws + 9655296);             // 102,760,448 B

  prep_w1<<<dim3(49), dim3(256), 0, stream>>>(W1, W1P);
  prep_w2<<<dim3(49), dim3(256), 0, stream>>>(M, W2, W2P);
  prep_b2<<<dim3((NH * DD + 255) / 256), dim3(256), 0, stream>>>(M, b2, b2sum);
  chiA<<<dim3(128 * 49), dim3(256), 0, stream>>>(x, M, W1P, b1, H);
  chiB<<<dim3(7168), dim3(256), 0, stream>>>(H, x, M, W2P, b2sum, out);
}

// Round 6
// 485.762 us; speedup vs baseline: 1.4624x; 1.3105x over previous
//
#include <hip/hip_runtime.h>
#include <hip/hip_bf16.h>
#include <math.h>

// Problem constants
#define NH   7        // hazards
#define NROW 16384    // B*S = 8*2048
#define DD   768      // hidden dim
#define KK   64       // bottleneck dim
#define THRG 0.05f

typedef float  f32x4   __attribute__((ext_vector_type(4)));
typedef __bf16 bf16x8  __attribute__((ext_vector_type(8)));
typedef short  short8v __attribute__((ext_vector_type(8)));
typedef short  short4v __attribute__((ext_vector_type(4)));

union V8 { short8v s; bf16x8 b; };

__device__ __forceinline__ float gate_of(const float* __restrict__ M, int s, int t) {
  float m = M[s * NH + t];
  return (s != t && fabsf(m) > THRG) ? m : 0.0f;
}

__device__ __forceinline__ float gelu_t(float v) {
  float u = 0.7978845608028654f * (v + 0.044715f * v * v * v);
  return v / (1.0f + __expf(-2.0f * u));   // v * sigmoid(2u)
}

// async 16B global -> LDS copy; lds ptr must be the WAVE-uniform base (HW adds lane*16)
__device__ __forceinline__ void gload_lds16(const void* g, void* l) {
  __builtin_amdgcn_global_load_lds(
      (const __attribute__((address_space(1))) unsigned int*)g,
      (__attribute__((address_space(3))) unsigned int*)l, 16, 0, 0);
}

// ---- prep: W1 [s][t][d][k] f32 -> W1P [pr][kc][kcol(64)][dl(64)] bf16,
// PRE-SWIZZLED (inverse of the LDS read XOR) so global_load_lds can copy linearly.
// (Layout + gload_lds staging verified correct in the R2 passing build.)
__global__ void prep_w1(const float* __restrict__ W1, unsigned short* __restrict__ W1P) {
  int pr = blockIdx.x;                       // pr = s*7+t
  const float* src = W1 + (size_t)pr * DD * KK;
  __bf16* dst = (__bf16*)(W1P + (size_t)pr * 12 * 4096);
  for (int idx = threadIdx.x; idx < 12 * 4096; idx += blockDim.x) {
    int kc = idx >> 12, rem = idx & 4095;
    int kcol = rem >> 6, dl = rem & 63;
    int dl_log = dl ^ ((kcol & 7) << 3);     // elem-space inverse of byte XOR ((row&7)<<4)
    dst[idx] = (__bf16)src[(size_t)(kc * 64 + dl_log) * KK + kcol];
  }
}

// ---- prep: W2 [s][t][k][d] f32 -> W2P [(t*7+s)*6+nb][dloc(128)][k(64)] bf16, gate folded
__global__ void prep_w2(const float* __restrict__ M, const float* __restrict__ W2,
                        unsigned short* __restrict__ W2P) {
  int st = blockIdx.x;                       // st = s*7+t
  int s = st / NH, t = st % NH;
  float g = gate_of(M, s, t);
  const float* src = W2 + (size_t)st * KK * DD;
  __bf16* dst = (__bf16*)(W2P + (size_t)((t * NH + s) * 6) * 8192);
  for (int idx = threadIdx.x; idx < 6 * 128 * 64; idx += blockDim.x) {
    int nb = idx >> 13, rem = idx & 8191;
    int dloc = rem >> 6, k = rem & 63;
    dst[idx] = (__bf16)(g * src[(size_t)k * DD + nb * 128 + dloc]);
  }
}

// ---- prep: b2sum[t][d] = sum_s gate(s,t) * b2[s][t][d]
__global__ void prep_b2(const float* __restrict__ M, const float* __restrict__ b2,
                        float* __restrict__ b2sum) {
  int idx = blockIdx.x * blockDim.x + threadIdx.x;
  if (idx >= NH * DD) return;
  int t = idx / DD, d = idx % DD;
  float acc = 0.f;
  for (int s = 0; s < NH; ++s)
    acc += gate_of(M, s, t) * b2[(size_t)(s * NH + t) * DD + d];
  b2sum[idx] = acc;
}

// ---- Phase A: H[pr][row][kcol] = gelu(x[s] W1[s,t] + b1)  (bf16, gate NOT applied)
// Baseline 244us structure, two surgical fixes per R0 counters (VALU 30% >> Mfma 11%):
//  (1) f2bf (4 VALU/elem) -> native (__bf16) casts (v_cvt_pk, ~8x fewer VALU ops)
//  (2) W1 staging -> global_load_lds from pre-swizzled W1P (no VGPR round-trip);
//      issued right after the barrier so the DMA overlaps the x staging VALU.
__global__ __launch_bounds__(256, 3)
void chiA(const float* __restrict__ x, const float* __restrict__ M,
          const unsigned short* __restrict__ W1P, const float* __restrict__ b1,
          unsigned short* __restrict__ H) {
  __shared__ __align__(16) unsigned short xs[128 * 64];   // 16 KB, swizzled [xrow][d]
  __shared__ __align__(16) unsigned short w1s[64 * 64];   //  8 KB, swizzled [kcol][d]

  int bid = (int)blockIdx.x;
  int nid = (bid & 7) * 784 + (bid >> 3);   // 6272 = 8*784; t innermost -> L2 reuse of x chunk
  int rb = nid / 49, pr = nid % 49;
  int s = pr / NH, t = pr % NH;
  if (gate_of(M, s, t) == 0.0f) return;
  int row0 = rb * 128;

  int tid = (int)threadIdx.x;
  int wid = tid >> 6, lane = tid & 63, l16 = lane & 15, l4 = lane >> 4;

  const f32x4 zero = {0.f, 0.f, 0.f, 0.f};
  f32x4 acc[4][2];
#pragma unroll
  for (int m = 0; m < 4; ++m)
#pragma unroll
    for (int n = 0; n < 2; ++n) acc[m][n] = zero;

  const float* xb = x + ((size_t)s * NROW + row0) * DD;
  const char* w1b = (const char*)(W1P + (size_t)pr * 12 * 4096);

  for (int kc = 0; kc < 12; ++kc) {
    __syncthreads();   // protect LDS from previous step's readers
    // W1 chunk: async DMA 8 KB (pre-swizzled source, linear dest) — overlaps x staging
    {
      const char* wsrc = w1b + (size_t)kc * 8192;
      char* wdst = (char*)w1s + (wid << 10);
#pragma unroll
      for (int r = 0; r < 2; ++r)
        gload_lds16(wsrc + r * 4096 + tid * 16, wdst + r * 4096);
    }
    // stage x chunk [128 rows][64 d] f32 -> bf16 (v_cvt_pk) swizzled
#pragma unroll
    for (int r = 0; r < 4; ++r) {
      int L = r * 4096 + tid * 16;          // byte offset in chunk
      int row = L >> 7, colB = L & 127;     // col = colB/2 (elems)
      const float* gp = xb + (size_t)row * DD + kc * 64 + (colB >> 1);
      f32x4 v0 = *(const f32x4*)gp;
      f32x4 v1 = *(const f32x4*)(gp + 4);
      bf16x8 sv;
      sv[0] = (__bf16)v0[0]; sv[1] = (__bf16)v0[1];
      sv[2] = (__bf16)v0[2]; sv[3] = (__bf16)v0[3];
      sv[4] = (__bf16)v1[0]; sv[5] = (__bf16)v1[1];
      sv[6] = (__bf16)v1[2]; sv[7] = (__bf16)v1[3];
      *(bf16x8*)((char*)xs + (L ^ ((row & 7) << 4))) = sv;
    }
    __syncthreads();   // drains vmcnt (gload_lds) + lgkm (ds_writes)

    V8 af[4][2], bf2[2][2];
#pragma unroll
    for (int mm = 0; mm < 4; ++mm)
#pragma unroll
      for (int k2 = 0; k2 < 2; ++k2) {
        int rowl = mm * 16 + l16;
        int byte = (rowl * 128 + k2 * 64 + l4 * 16) ^ ((rowl & 7) << 4);
        af[mm][k2].s = *(const short8v*)((const char*)w1s + byte);
      }
#pragma unroll
    for (int nn = 0; nn < 2; ++nn)
#pragma unroll
      for (int k2 = 0; k2 < 2; ++k2) {
        int xr = wid * 32 + nn * 16 + l16;
        int byte = (xr * 128 + k2 * 64 + l4 * 16) ^ ((xr & 7) << 4);
        bf2[nn][k2].s = *(const short8v*)((const char*)xs + byte);
      }
#pragma unroll
    for (int k2 = 0; k2 < 2; ++k2)
#pragma unroll
      for (int mm = 0; mm < 4; ++mm)
#pragma unroll
        for (int nn = 0; nn < 2; ++nn)
          acc[mm][nn] = __builtin_amdgcn_mfma_f32_16x16x32_bf16(af[mm][k2].b, bf2[nn][k2].b, acc[mm][nn], 0, 0, 0);
  }

  // epilogue: +b1, gelu, store bf16 H (contiguous short4 along kcol)
#pragma unroll
  for (int mm = 0; mm < 4; ++mm) {
    f32x4 bv = *(const f32x4*)(b1 + (size_t)pr * KK + mm * 16 + l4 * 4);
#pragma unroll
    for (int nn = 0; nn < 2; ++nn) {
      union { short4v s4; __bf16 b4[4]; } o;
#pragma unroll
      for (int r = 0; r < 4; ++r) o.b4[r] = (__bf16)gelu_t(acc[mm][nn][r] + bv[r]);
      int xrow = row0 + wid * 32 + nn * 16 + l16;
      unsigned short* hp = H + ((size_t)pr * NROW + xrow) * KK + mm * 16 + l4 * 4;
      *(short4v*)hp = o.s4;
    }
  }
}

// ---- Phase B: out[t] = x[t] + sum_s H[s,t](128xK) * W2P[t,s](Kx128) + b2sum[t]
// R4's measured variant (~233us): baseline staging (hs + w2s, 2 barriers/source),
// SWAPPED operands (A = w2s dloc rows, B = hs x rows) so the D-frag's 4 regs run
// along output columns -> coalesced f32x4 residual loads + stores.
__global__ __launch_bounds__(256, 4)
void chiB(const unsigned short* __restrict__ H, const float* __restrict__ x,
          const float* __restrict__ M, const unsigned short* __restrict__ W2P,
          const float* __restrict__ b2sum, float* __restrict__ out) {
  __shared__ __align__(16) unsigned short hs[128 * 64];   // 16 KB, swizzled [row][k]
  __shared__ __align__(16) unsigned short w2s[128 * 64];  // 16 KB, swizzled [dloc][k]

  int bid = (int)blockIdx.x;
  int nid = (bid & 7) * 672 + (bid >> 3);   // 5376 = 8*672; nb innermost -> L2 reuse of H chunk
  int nb = nid % 6, rem = nid / 6;
  int rb = rem % 128, t = rem / 128;
  int row0 = rb * 128, col0 = nb * 128;

  int tid = (int)threadIdx.x;
  int wid = tid >> 6, lane = tid & 63, l16 = lane & 15, l4 = lane >> 4;
  int wr = wid & 1, wc = wid >> 1;          // wave = 64 rows x 64 cols of the 128x128 tile

  const f32x4 zero = {0.f, 0.f, 0.f, 0.f};
  f32x4 acc[4][4];                          // [m]=col tiles, [n]=row tiles
#pragma unroll
  for (int m = 0; m < 4; ++m)
#pragma unroll
    for (int n = 0; n < 4; ++n) acc[m][n] = zero;

  for (int s = 0; s < NH; ++s) {
    if (gate_of(M, s, t) == 0.0f) continue;
    __syncthreads();   // protect LDS from previous step's readers
    const char* hb = (const char*)(H + ((size_t)(s * NH + t) * NROW + row0) * KK);
    const char* wb = (const char*)(W2P + (size_t)((t * NH + s) * 6 + nb) * 8192);
#pragma unroll
    for (int r = 0; r < 4; ++r) {
      int L = r * 4096 + tid * 16;
      int row = L >> 7;
      short8v v = *(const short8v*)(hb + L);
      *(short8v*)((char*)hs + (L ^ ((row & 7) << 4))) = v;
      short8v w = *(const short8v*)(wb + L);
      *(short8v*)((char*)w2s + (L ^ ((row & 7) << 4))) = w;
    }
    __syncthreads();

    V8 af[4][2], bfr[4][2];
#pragma unroll
    for (int m = 0; m < 4; ++m)                 // A: W2 dloc rows (output columns)
#pragma unroll
      for (int k2 = 0; k2 < 2; ++k2) {
        int dl = wc * 64 + m * 16 + l16;
        int byte = (dl * 128 + k2 * 64 + l4 * 16) ^ ((dl & 7) << 4);
        af[m][k2].s = *(const short8v*)((const char*)w2s + byte);
      }
#pragma unroll
    for (int n = 0; n < 4; ++n)                 // B: H rows (output rows)
#pragma unroll
      for (int k2 = 0; k2 < 2; ++k2) {
        int rl = wr * 64 + n * 16 + l16;
        int byte = (rl * 128 + k2 * 64 + l4 * 16) ^ ((rl & 7) << 4);
        bfr[n][k2].s = *(const short8v*)((const char*)hs + byte);
      }
#pragma unroll
    for (int k2 = 0; k2 < 2; ++k2)
#pragma unroll
      for (int m = 0; m < 4; ++m)
#pragma unroll
        for (int n = 0; n < 4; ++n)
          acc[m][n] = __builtin_amdgcn_mfma_f32_16x16x32_bf16(af[m][k2].b, bfr[n][k2].b, acc[m][n], 0, 0, 0);
  }

  // epilogue: + x residual (exact f32) + b2sum; coalesced f32x4 along columns
#pragma unroll
  for (int m = 0; m < 4; ++m) {
    int col = col0 + wc * 64 + m * 16 + l4 * 4;
    f32x4 bv = *(const f32x4*)(b2sum + (size_t)t * DD + col);
#pragma unroll
    for (int n = 0; n < 4; ++n) {
      int row = row0 + wr * 64 + n * 16 + l16;
      size_t off = ((size_t)t * NROW + row) * DD + col;
      f32x4 xv = *(const f32x4*)(x + off);
      f32x4 ov;
#pragma unroll
      for (int r = 0; r < 4; ++r) ov[r] = acc[m][n][r] + xv[r] + bv[r];
      *(f32x4*)(out + off) = ov;
    }
  }
}

extern "C" void kernel_launch(void* const* d_in, const int* in_sizes, int n_in,
                              void* d_out, int out_size, void* d_ws, size_t ws_size,
                              hipStream_t stream) {
  const float* x  = (const float*)d_in[0];
  const float* M  = (const float*)d_in[1];
  const float* W1 = (const float*)d_in[2];
  const float* b1 = (const float*)d_in[3];
  const float* W2 = (const float*)d_in[4];
  const float* b2 = (const float*)d_in[5];
  float* out = (float*)d_out;

  char* ws = (char*)d_ws;
  unsigned short* W1P = (unsigned short*)ws;                         // 4,816,896 B
  unsigned short* W2P = (unsigned short*)(ws + 4816896);             // 4,816,896 B
  float* b2sum        = (float*)(ws + 9633792);                      // 21,504 B
  unsigned short* H   = (unsigned short*)(ws + 9655296);             // 102,760,448 B

  prep_w1<<<dim3(49), dim3(256), 0, stream>>>(W1, W1P);
  prep_w2<<<dim3(49), dim3(256), 0, stream>>>(M, W2, W2P);
  prep_b2<<<dim3((NH * DD + 255) / 256), dim3(256), 0, stream>>>(M, b2, b2sum);
  chiA<<<dim3(128 * 49), dim3(256), 0, stream>>>(x, M, W1P, b1, H);
  chiB<<<dim3(NH * 128 * 6), dim3(256), 0, stream>>>(H, x, M, W2P, b2sum, out);
}